// Round 5
// baseline (50.309 us; speedup 1.0000x reference)
//
#include <hip/hip_runtime.h>

__device__ __forceinline__ float frcp(float x){ return __builtin_amdgcn_rcpf(x); }

// Liang-Barsky clip of segment E0->E1 against axis-aligned box [lx,hx]x[ly,hy].
// Returns cross(P(t0), P(t1)) of the kept sub-segment, 0 if empty.
// (0*inf NaN cases are measure-zero and washed out by the 500k mean.)
__device__ __forceinline__ float lb_edge(float x0, float y0, float x1, float y1,
                                         float lx, float hx, float ly, float hy)
{
    float dx = x1 - x0, dy = y1 - y0;
    float idx = frcp(dx), idy = frcp(dy);
    float ta = (lx - x0) * idx, tb = (hx - x0) * idx;
    float tc = (ly - y0) * idy, td = (hy - y0) * idy;
    float tx0 = fminf(ta, tb), tx1 = fmaxf(ta, tb);
    float ty0 = fminf(tc, td), ty1 = fmaxf(tc, td);
    float t0 = fmaxf(fmaxf(tx0, ty0), 0.f);   // -> v_max3
    float t1 = fminf(fminf(tx1, ty1), 1.f);   // -> v_min3
    bool valid = t1 > t0;
    float pax = fmaf(t0, dx, x0), pay = fmaf(t0, dy, y0);
    float pbx = fmaf(t1, dx, x0), pby = fmaf(t1, dy, y0);
    float c = fmaf(pax, pby, -pay * pbx);
    return valid ? c : 0.f;
}

// 4 CCW corners (cx +- ux +- vx pattern matching ref DX/DY order) clipped vs box
__device__ __forceinline__ float clip_quad(float cbx, float cby,
                                           float ux, float uy, float vx, float vy,
                                           float lx, float hx, float ly, float hy)
{
    float upx = ux + vx, upy = uy + vy;
    float umx = ux - vx, umy = uy - vy;
    float gx0 = cbx + upx, gy0 = cby + upy;   // (+,+)
    float gx1 = cbx - umx, gy1 = cby - umy;   // (-,+)
    float gx2 = cbx - upx, gy2 = cby - upy;   // (-,-)
    float gx3 = cbx + umx, gy3 = cby + umy;   // (+,-)
    float s = lb_edge(gx0, gy0, gx1, gy1, lx, hx, ly, hy);
    s += lb_edge(gx1, gy1, gx2, gy2, lx, hx, ly, hy);
    s += lb_edge(gx2, gy2, gx3, gy3, lx, hx, ly, hy);
    s += lb_edge(gx3, gy3, gx0, gy0, lx, hx, ly, hy);
    return s;
}

__global__ __launch_bounds__(256) void giou_kernel(
    const float* __restrict__ pred, const float* __restrict__ target,
    float* __restrict__ partial, unsigned int* __restrict__ counter,
    float* __restrict__ out, int n, float invn)
{
    int i = blockIdx.x * blockDim.x + threadIdx.x;
    float loss = 0.0f;
    if (i < n) {
        const float p0 = pred[5*i+0], p1 = pred[5*i+1], p2 = pred[5*i+2], p3 = pred[5*i+3], p4 = pred[5*i+4];
        const float q0 = target[5*i+0], q1 = target[5*i+1], q2 = target[5*i+2], q3 = target[5*i+3], q4 = target[5*i+4];

        // A center relative to midpoint of centers; B center is exactly -oa
        const float oaX = 0.5f*(p0 - q0), oaY = 0.5f*(p1 - q1);
        const float hw1 = 0.5f*p2, hh1 = 0.5f*p3, hw2 = 0.5f*q2, hh2 = 0.5f*q3;

        const float cs1 = __cosf(p4), sn1 = __sinf(p4);
        const float cs2 = __cosf(q4), sn2 = __sinf(q4);
        const float cD = cs1*cs2 + sn1*sn2;   // cos(a2-a1)
        const float sD = sn2*cs1 - cs2*sn1;   // sin(a2-a1)

        // ---- frame A (rotate world by -a1, origin = midpoint) ----
        const float caX =  oaX*cs1 + oaY*sn1;   // A center in frame A
        const float caY = -oaX*sn1 + oaY*cs1;
        // B in frame A: center -ca, half-edge vectors u=R(D)(hw2,0), v=R(D)(0,hh2)
        float twoA = clip_quad(-caX, -caY,
                               cD*hw2,  sD*hw2, -sD*hh2, cD*hh2,
                               caX - hw1, caX + hw1, caY - hh1, caY + hh1);

        // ---- frame B (rotate world by -a2) ----
        const float caX2 =  oaX*cs2 + oaY*sn2;  // A center in frame B
        const float caY2 = -oaX*sn2 + oaY*cs2;
        // A in frame B: center +ca2, u2=R(-D)(hw1,0), v2=R(-D)(0,hh1); box B at -ca2
        twoA += clip_quad(caX2, caY2,
                          cD*hw1, -sD*hw1, sD*hh1, cD*hh1,
                          -caX2 - hw2, -caX2 + hw2, -caY2 - hh2, -caY2 + hh2);

        float inter_area = 0.5f * fabsf(twoA);

        // ---- union / iou ----
        float unionv = p2*p3 + q2*q3 - inter_area;
        float iou = fmaxf(inter_area * frcp(unionv), 1e-6f);

        // ---- smallest enclosing rect: 2 distinct directions, closed form ----
        float acd = fabsf(cD), asd = fabsf(sD);
        // direction = box1 axes (projected centers are +-ca in frame A)
        float eBx = hw2*acd + hh2*asd, eBy = hw2*asd + hh2*acd;
        float w1 = fmaxf(caX + hw1, -caX + eBx) - fminf(caX - hw1, -caX - eBx);
        float h1 = fmaxf(caY + hh1, -caY + eBy) - fminf(caY - hh1, -caY - eBy);
        float a1 = w1*h1;
        // direction = box2 axes
        float eAx = hw1*acd + hh1*asd, eAy = hw1*asd + hh1*acd;
        float w2 = fmaxf(caX2 + eAx, -caX2 + hw2) - fminf(caX2 - eAx, -caX2 - hw2);
        float h2 = fmaxf(caY2 + eAy, -caY2 + hh2) - fminf(caY2 - eAy, -caY2 - hh2);
        float a2 = w2*h2;

        float area_c = (a2 < a1) ? a2 : a1;   // box1 dirs first in ref argmin

        float r = (area_c - unionv) * frcp(area_c);
        float giou = iou*iou*iou - r*r*r;
        loss = 1.0f - giou;
    }

    // ---- deterministic block reduction ----
    #pragma unroll
    for (int off = 32; off; off >>= 1) loss += __shfl_down(loss, off, 64);
    __shared__ float smem[4];
    __shared__ int is_last;
    int lane = threadIdx.x & 63, wid = threadIdx.x >> 6;
    if (lane == 0) smem[wid] = loss;
    __syncthreads();
    if (threadIdx.x == 0) {
        partial[blockIdx.x] = smem[0] + smem[1] + smem[2] + smem[3];
        __threadfence();                                   // release partial
        unsigned int t = atomicAdd(counter, 1u);           // device-scope ticket
        is_last = (t == gridDim.x - 1) ? 1 : 0;
    }
    __syncthreads();

    // ---- last block: final reduce in fixed index order (bit-deterministic) ----
    if (is_last) {
        __threadfence();                                   // acquire partials
        float s = 0.f;
        for (int k = threadIdx.x; k < (int)gridDim.x; k += 256) s += partial[k];
        #pragma unroll
        for (int off = 32; off; off >>= 1) s += __shfl_down(s, off, 64);
        __syncthreads();
        if (lane == 0) smem[wid] = s;
        __syncthreads();
        if (threadIdx.x == 0) {
            out[0] = (smem[0] + smem[1] + smem[2] + smem[3]) * invn;
        }
    }
}

extern "C" void kernel_launch(void* const* d_in, const int* in_sizes, int n_in,
                              void* d_out, int out_size, void* d_ws, size_t ws_size,
                              hipStream_t stream) {
    const float* pred   = (const float*)d_in[0];
    const float* target = (const float*)d_in[1];
    float* out = (float*)d_out;
    unsigned int* counter = (unsigned int*)d_ws;           // 4B ticket at ws[0]
    float* partial = (float*)((char*)d_ws + 256);          // partials after it
    int n  = in_sizes[0] / 5;
    int nb = (n + 255) / 256;
    hipMemsetAsync(counter, 0, 4, stream);                 // reset ticket (memset node)
    giou_kernel<<<nb, 256, 0, stream>>>(pred, target, partial, counter, out, n, 1.0f/(float)n);
}

// Round 6
// 15.514 us; speedup vs baseline: 3.2428x; 3.2428x over previous
//
#include <hip/hip_runtime.h>

__device__ __forceinline__ float frcp(float x){ return __builtin_amdgcn_rcpf(x); }

// Liang-Barsky clip of segment E0->E1 against axis-aligned box [lx,hx]x[ly,hy].
// Returns cross(P(t0), P(t1)) of the kept sub-segment, 0 if empty.
// (0*inf NaN cases are measure-zero and washed out by the 500k mean.)
__device__ __forceinline__ float lb_edge(float x0, float y0, float x1, float y1,
                                         float lx, float hx, float ly, float hy)
{
    float dx = x1 - x0, dy = y1 - y0;
    float idx = frcp(dx), idy = frcp(dy);
    float ta = (lx - x0) * idx, tb = (hx - x0) * idx;
    float tc = (ly - y0) * idy, td = (hy - y0) * idy;
    float tx0 = fminf(ta, tb), tx1 = fmaxf(ta, tb);
    float ty0 = fminf(tc, td), ty1 = fmaxf(tc, td);
    float t0 = fmaxf(fmaxf(tx0, ty0), 0.f);   // -> v_max3
    float t1 = fminf(fminf(tx1, ty1), 1.f);   // -> v_min3
    bool valid = t1 > t0;
    float pax = fmaf(t0, dx, x0), pay = fmaf(t0, dy, y0);
    float pbx = fmaf(t1, dx, x0), pby = fmaf(t1, dy, y0);
    float c = fmaf(pax, pby, -pay * pbx);
    return valid ? c : 0.f;
}

// 4 CCW corners (cx +- ux +- vx pattern matching ref DX/DY order) clipped vs box
__device__ __forceinline__ float clip_quad(float cbx, float cby,
                                           float ux, float uy, float vx, float vy,
                                           float lx, float hx, float ly, float hy)
{
    float upx = ux + vx, upy = uy + vy;
    float umx = ux - vx, umy = uy - vy;
    float gx0 = cbx + upx, gy0 = cby + upy;   // (+,+)
    float gx1 = cbx - umx, gy1 = cby - umy;   // (-,+)
    float gx2 = cbx - upx, gy2 = cby - upy;   // (-,-)
    float gx3 = cbx + umx, gy3 = cby + umy;   // (+,-)
    float s = lb_edge(gx0, gy0, gx1, gy1, lx, hx, ly, hy);
    s += lb_edge(gx1, gy1, gx2, gy2, lx, hx, ly, hy);
    s += lb_edge(gx2, gy2, gx3, gy3, lx, hx, ly, hy);
    s += lb_edge(gx3, gy3, gx0, gy0, lx, hx, ly, hy);
    return s;
}

__global__ __launch_bounds__(256) void giou_partial_kernel(
    const float* __restrict__ pred, const float* __restrict__ target,
    float* __restrict__ partial, int n)
{
    int i = blockIdx.x * blockDim.x + threadIdx.x;
    float loss = 0.0f;
    if (i < n) {
        const float p0 = pred[5*i+0], p1 = pred[5*i+1], p2 = pred[5*i+2], p3 = pred[5*i+3], p4 = pred[5*i+4];
        const float q0 = target[5*i+0], q1 = target[5*i+1], q2 = target[5*i+2], q3 = target[5*i+3], q4 = target[5*i+4];

        // A center relative to midpoint of centers; B center is exactly -oa
        const float oaX = 0.5f*(p0 - q0), oaY = 0.5f*(p1 - q1);
        const float hw1 = 0.5f*p2, hh1 = 0.5f*p3, hw2 = 0.5f*q2, hh2 = 0.5f*q3;

        const float cs1 = __cosf(p4), sn1 = __sinf(p4);
        const float cs2 = __cosf(q4), sn2 = __sinf(q4);
        const float cD = cs1*cs2 + sn1*sn2;   // cos(a2-a1)
        const float sD = sn2*cs1 - cs2*sn1;   // sin(a2-a1)

        // ---- frame A (rotate world by -a1, origin = midpoint) ----
        const float caX =  oaX*cs1 + oaY*sn1;   // A center in frame A
        const float caY = -oaX*sn1 + oaY*cs1;
        // B in frame A: center -ca, half-edge vectors u=R(D)(hw2,0), v=R(D)(0,hh2)
        float twoA = clip_quad(-caX, -caY,
                               cD*hw2,  sD*hw2, -sD*hh2, cD*hh2,
                               caX - hw1, caX + hw1, caY - hh1, caY + hh1);

        // ---- frame B (rotate world by -a2) ----
        const float caX2 =  oaX*cs2 + oaY*sn2;  // A center in frame B
        const float caY2 = -oaX*sn2 + oaY*cs2;
        // A in frame B: center +ca2, u2=R(-D)(hw1,0), v2=R(-D)(0,hh1); box B at -ca2
        twoA += clip_quad(caX2, caY2,
                          cD*hw1, -sD*hw1, sD*hh1, cD*hh1,
                          -caX2 - hw2, -caX2 + hw2, -caY2 - hh2, -caY2 + hh2);

        float inter_area = 0.5f * fabsf(twoA);

        // ---- union / iou ----
        float unionv = p2*p3 + q2*q3 - inter_area;
        float iou = fmaxf(inter_area * frcp(unionv), 1e-6f);

        // ---- smallest enclosing rect: 2 distinct directions, closed form ----
        float acd = fabsf(cD), asd = fabsf(sD);
        // direction = box1 axes (projected centers are +-ca in frame A)
        float eBx = hw2*acd + hh2*asd, eBy = hw2*asd + hh2*acd;
        float w1 = fmaxf(caX + hw1, -caX + eBx) - fminf(caX - hw1, -caX - eBx);
        float h1 = fmaxf(caY + hh1, -caY + eBy) - fminf(caY - hh1, -caY - eBy);
        float a1 = w1*h1;
        // direction = box2 axes
        float eAx = hw1*acd + hh1*asd, eAy = hw1*asd + hh1*acd;
        float w2 = fmaxf(caX2 + eAx, -caX2 + hw2) - fminf(caX2 - eAx, -caX2 - hw2);
        float h2 = fmaxf(caY2 + eAy, -caY2 + hh2) - fminf(caY2 - eAy, -caY2 - hh2);
        float a2 = w2*h2;

        float area_c = (a2 < a1) ? a2 : a1;   // box1 dirs first in ref argmin

        float r = (area_c - unionv) * frcp(area_c);
        float giou = iou*iou*iou - r*r*r;
        loss = 1.0f - giou;
    }

    // ---- deterministic block reduction ----
    #pragma unroll
    for (int off = 32; off; off >>= 1) loss += __shfl_down(loss, off, 64);
    __shared__ float smem[4];
    int lane = threadIdx.x & 63, wid = threadIdx.x >> 6;
    if (lane == 0) smem[wid] = loss;
    __syncthreads();
    if (threadIdx.x == 0) {
        partial[blockIdx.x] = smem[0] + smem[1] + smem[2] + smem[3];
    }
}

__global__ __launch_bounds__(256) void reduce_final_kernel(
    const float* __restrict__ partial, int nb, float* __restrict__ out, float invn)
{
    float s = 0.f;
    for (int i = threadIdx.x; i < nb; i += 256) s += partial[i];
    #pragma unroll
    for (int off = 32; off; off >>= 1) s += __shfl_down(s, off, 64);
    __shared__ float smem[4];
    int lane = threadIdx.x & 63, wid = threadIdx.x >> 6;
    if (lane == 0) smem[wid] = s;
    __syncthreads();
    if (threadIdx.x == 0) {
        out[0] = (smem[0] + smem[1] + smem[2] + smem[3]) * invn;
    }
}

extern "C" void kernel_launch(void* const* d_in, const int* in_sizes, int n_in,
                              void* d_out, int out_size, void* d_ws, size_t ws_size,
                              hipStream_t stream) {
    const float* pred   = (const float*)d_in[0];
    const float* target = (const float*)d_in[1];
    float* out = (float*)d_out;
    float* partial = (float*)d_ws;
    int n  = in_sizes[0] / 5;
    int nb = (n + 255) / 256;
    giou_partial_kernel<<<nb, 256, 0, stream>>>(pred, target, partial, n);
    reduce_final_kernel<<<1, 256, 0, stream>>>(partial, nb, out, 1.0f/(float)n);
}